// Round 8
// baseline (21.289 us; speedup 1.0000x reference)
//
#include <hip/hip_runtime.h>
#include <cmath>

#define NMAX    8
#define NM      25
#define GSLOTS  24     // per-species slab rows
#define ROWW    44     // row stride (floats): 12 mod 32 -> spread bank groups
#define NOUT    1080
#define CROW    36     // c row: l-blocks packed 4+4+8+8+12, pads zeroed
#define CSLICE  288    // 8 * 36

struct Params {
    float W[NMAX * NMAX];
    float invnorm[NMAX];
    float ycoef[NM];        // sph-harm coefficients * 4*pi
    float lscale[5];
    float pairf[6];
};

// heavy per-neighbor compute: writes g[8] + permuted Y into row (10 x b128)
__device__ __forceinline__ void neighbor_compute(const Params& prm,
                                                 float dx, float dy, float dz,
                                                 float* __restrict__ row) {
    const float d2 = dx * dx + dy * dy + dz * dz;
    const float dist = sqrtf(d2);
    const float inv  = dist > 0.f ? 1.f / dist : 0.f;
    const float x = dx * inv, y = dy * inv, z = dz * inv;
    const float x2 = x * x, y2 = y * y, z2 = z * z;
    const float r2 = x2 + y2 + z2;

    const float dr = 5.f - dist;
    float bas[NMAX];
    float drp = dr * dr * dr;
#pragma unroll
    for (int a = 0; a < NMAX; ++a) { bas[a] = drp * prm.invnorm[a]; drp *= dr; }
    float g[NMAX];
#pragma unroll
    for (int n = 0; n < NMAX; ++n) {
        float acc = 0.f;
#pragma unroll
        for (int a = 0; a < NMAX; ++a) acc += bas[a] * prm.W[n * NMAX + a];
        g[n] = acc;
    }

    float Yv[NM];
    Yv[0]  = prm.ycoef[0];
    Yv[1]  = prm.ycoef[1]  * y;
    Yv[2]  = prm.ycoef[2]  * z;
    Yv[3]  = prm.ycoef[3]  * x;
    Yv[4]  = prm.ycoef[4]  * x * y;
    Yv[5]  = prm.ycoef[5]  * y * z;
    Yv[6]  = prm.ycoef[6]  * (3.f * z2 - r2);
    Yv[7]  = prm.ycoef[7]  * x * z;
    Yv[8]  = prm.ycoef[8]  * (x2 - y2);
    Yv[9]  = prm.ycoef[9]  * y * (3.f * x2 - y2);
    Yv[10] = prm.ycoef[10] * x * y * z;
    Yv[11] = prm.ycoef[11] * y * (5.f * z2 - r2);
    Yv[12] = prm.ycoef[12] * z * (5.f * z2 - 3.f * r2);
    Yv[13] = prm.ycoef[13] * x * (5.f * z2 - r2);
    Yv[14] = prm.ycoef[14] * z * (x2 - y2);
    Yv[15] = prm.ycoef[15] * x * (x2 - 3.f * y2);
    Yv[16] = prm.ycoef[16] * x * y * (x2 - y2);
    Yv[17] = prm.ycoef[17] * y * z * (3.f * x2 - y2);
    Yv[18] = prm.ycoef[18] * x * y * (7.f * z2 - r2);
    Yv[19] = prm.ycoef[19] * y * z * (7.f * z2 - 3.f * r2);
    Yv[20] = prm.ycoef[20] * (35.f * z2 * z2 - 30.f * z2 * r2 + 3.f * r2 * r2);
    Yv[21] = prm.ycoef[21] * x * z * (7.f * z2 - 3.f * r2);
    Yv[22] = prm.ycoef[22] * (x2 - y2) * (7.f * z2 - r2);
    Yv[23] = prm.ycoef[23] * x * z * (x2 - 3.f * y2);
    Yv[24] = prm.ycoef[24] * (x2 * x2 - 6.f * x2 * y2 + y2 * y2);

    // permuted: quad[2+mrow] = {Y[mrow], Y[mrow+8], Y[mrow+16], Y[mrow+24]|0}
    float4* q = (float4*)row;
    q[0] = make_float4(g[0], g[1], g[2], g[3]);
    q[1] = make_float4(g[4], g[5], g[6], g[7]);
    q[2] = make_float4(Yv[0], Yv[8],  Yv[16], Yv[24]);
    q[3] = make_float4(Yv[1], Yv[9],  Yv[17], 0.f);
    q[4] = make_float4(Yv[2], Yv[10], Yv[18], 0.f);
    q[5] = make_float4(Yv[3], Yv[11], Yv[19], 0.f);
    q[6] = make_float4(Yv[4], Yv[12], Yv[20], 0.f);
    q[7] = make_float4(Yv[5], Yv[13], Yv[21], 0.f);
    q[8] = make_float4(Yv[6], Yv[14], Yv[22], 0.f);
    q[9] = make_float4(Yv[7], Yv[15], Yv[23], 0.f);
}

__global__ __launch_bounds__(256)
void soap_kernel(const float* __restrict__ pos, const int* __restrict__ Z,
                 float* __restrict__ out, Params prm) {
    // one site per 256-thread block; waves 0-2 = species 0-2; ONE barrier; C on 4 waves
    __shared__ float4 dA[3][64];                       // per-species compacted (dx,dy,dz,·)
    __shared__ __align__(16) float gys[3][GSLOTS * ROWW];
    __shared__ __align__(16) float c2[3 * CSLICE];     // [s][n][36]

    const int tid  = threadIdx.x;
    const int lane = tid & 63;
    const int w    = tid >> 6;
    const int site = blockIdx.x;
    const int jbase = (site >> 9) << 9;
    const unsigned long long ltm = (1ull << lane) - 1ull;

    const float xi = pos[site * 3 + 0];
    const float yi = pos[site * 3 + 1];
    const float zi = pos[site * 3 + 2];

    if (w < 3) {
        const int s = w;
        // zero own c2 slice (pads must read 0): 288 floats = 72 quads
        float4* cz = (float4*)&c2[s * CSLICE];
        cz[lane & 63] = make_float4(0.f, 0.f, 0.f, 0.f);
        if (lane < 8) cz[64 + lane] = make_float4(0.f, 0.f, 0.f, 0.f);

        // ---- A1: species-filtered scan + ballot compaction ----
        int mtot = 0;
#pragma unroll
        for (int it = 0; it < 8; ++it) {
            const int ja = jbase + it * 64 + lane;
            const float dx = xi - pos[ja * 3 + 0];
            const float dy = yi - pos[ja * 3 + 1];
            const float dz = zi - pos[ja * 3 + 2];
            const float d2 = dx * dx + dy * dy + dz * dz;
            const int zz = Z[ja];
            const int sp = (zz == 1) ? 0 : (zz == 6) ? 1 : 2;
            const bool pr = (d2 < 25.0f) && (sp == s);
            const unsigned long long mk = __ballot(pr);
            if (pr) {
                const int sl = mtot + __popcll(mk & ltm);
                if (sl < 64) dA[s][sl] = make_float4(dx, dy, dz, 0.f);
            }
            mtot += __popcll(mk);
        }
        const int Ms = mtot;

        const int n_own = lane & 7;
        const int mrow  = lane >> 3;
        float a[4] = {0.f, 0.f, 0.f, 0.f};
        const float* yb = &gys[s][8 + 4 * mrow];

        if (Ms <= 64) {
            // ---- slab loop over compacted list ----
            for (int rb = 0; rb < Ms; rb += GSLOTS) {
                const int cnt = min(GSLOTS, Ms - rb);
                if (lane < cnt) {
                    const float4 u = dA[s][rb + lane];
                    neighbor_compute(prm, u.x, u.y, u.z, &gys[s][lane * ROWW]);
                }
                // in-wave DS ordering: writes above precede reads below
                for (int sl = 0; sl < cnt; ++sl) {
                    const float g  = gys[s][sl * ROWW + n_own];
                    const float4 y4 = *(const float4*)&yb[sl * ROWW];
                    a[0] += g * y4.x; a[1] += g * y4.y; a[2] += g * y4.z; a[3] += g * y4.w;
                }
            }
        } else {
            // ---- fallback (Ms > 64, practically unreachable): per-chunk ----
            for (int it = 0; it < 8; ++it) {
                const int ja = jbase + it * 64 + lane;
                const float dx = xi - pos[ja * 3 + 0];
                const float dy = yi - pos[ja * 3 + 1];
                const float dz = zi - pos[ja * 3 + 2];
                const float d2 = dx * dx + dy * dy + dz * dz;
                const int zz = Z[ja];
                const int sp = (zz == 1) ? 0 : (zz == 6) ? 1 : 2;
                const bool pr = (d2 < 25.0f) && (sp == s);
                const unsigned long long mk = __ballot(pr);
                const int cnt0 = __popcll(mk);
                if (pr) dA[s][__popcll(mk & ltm)] = make_float4(dx, dy, dz, 0.f);
                for (int rb = 0; rb < cnt0; rb += GSLOTS) {
                    const int cnt = min(GSLOTS, cnt0 - rb);
                    if (lane < cnt) {
                        const float4 u = dA[s][rb + lane];
                        neighbor_compute(prm, u.x, u.y, u.z, &gys[s][lane * ROWW]);
                    }
                    for (int sl = 0; sl < cnt; ++sl) {
                        const float g  = gys[s][sl * ROWW + n_own];
                        const float4 y4 = *(const float4*)&yb[sl * ROWW];
                        a[0] += g * y4.x; a[1] += g * y4.y; a[2] += g * y4.z; a[3] += g * y4.w;
                    }
                }
            }
        }

        // ---- write c slice: packed l-blocks, pads pre-zeroed ----
#pragma unroll
        for (int k = 0; k < 4; ++k) {
            const int m = mrow + 8 * k;
            if (m < NM) {
                const int l  = (int)sqrtf((float)m);   // exact at perfect squares
                const int kk = m - l * l;
                const int lofs = (l < 2) ? 4 * l : 8 * (l - 1);
                c2[s * CSLICE + n_own * CROW + lofs + kk] = a[k];
            }
        }
    }

    __syncthreads();

    // ---- C: 30 (q,l) items over 4 waves {8,8,7,7}; lane = (n,p) triu pair ----
    if (lane < 36) {
        const int t = lane;
        const int n = (int)((17.0f - sqrtf((float)(289 - 8 * t))) * 0.5f);
        const int p = t - ((n * (17 - n)) >> 1) + n;
        const float npf = (n != p) ? 1.41421356237309515f : 1.0f;
        const int start = (w < 2) ? 8 * w : 16 + 7 * (w - 2);
        const int icnt  = (w < 2) ? 8 : 7;
        for (int ii = 0; ii < icnt; ++ii) {
            const int item = start + ii;
            const int q = (item * 13) >> 6;      // item/5 for item<30
            const int l = item - 5 * q;
            const int s1 = (q < 3) ? 0 : ((q < 5) ? 1 : 2);
            const int s2 = (q < 3) ? q : ((q < 5) ? (q - 2) : 2);
            const int lofs = (l < 2) ? 4 * l : 8 * (l - 1);
            const int nq   = (l < 2) ? 1 : ((l < 4) ? 2 : 3);
            const float4* ra = (const float4*)&c2[s1 * CSLICE + n * CROW + lofs];
            const float4* rb = (const float4*)&c2[s2 * CSLICE + p * CROW + lofs];
            float sum = 0.f;
            for (int j = 0; j < nq; ++j) {
                const float4 av = ra[j], bv = rb[j];
                sum += av.x * bv.x + av.y * bv.y + av.z * bv.z + av.w * bv.w;
            }
            out[site * NOUT + q * 180 + l * 36 + t] = sum * prm.pairf[q] * prm.lscale[l] * npf;
        }
    }
}

extern "C" void kernel_launch(void* const* d_in, const int* in_sizes, int n_in,
                              void* d_out, int out_size, void* d_ws, size_t ws_size,
                              hipStream_t stream) {
    const float* pos = (const float*)d_in[0];
    const int*   Z   = (const int*)d_in[1];
    float*       out = (float*)d_out;
    const int nsite  = in_sizes[1];   // B*N = 2048

    Params prm;

    // ---- W_ORTHO = S^(-1/2) via cyclic Jacobi (double precision, host) ----
    double A[8][8], V[8][8];
    for (int i = 0; i < 8; ++i)
        for (int j = 0; j < 8; ++j) {
            const double ai = i + 1.0, aj = j + 1.0;
            A[i][j] = sqrt((5.0 + 2.0 * ai) * (5.0 + 2.0 * aj)) / (5.0 + ai + aj);
            V[i][j] = (i == j) ? 1.0 : 0.0;
        }
    for (int sweep = 0; sweep < 30; ++sweep) {
        for (int p = 0; p < 8; ++p)
            for (int q = p + 1; q < 8; ++q) {
                const double apq = A[p][q];
                if (fabs(apq) < 1e-300) continue;
                const double phi = 0.5 * atan2(2.0 * apq, A[q][q] - A[p][p]);
                const double c = cos(phi), s = sin(phi);
                for (int k = 0; k < 8; ++k) {
                    const double akp = A[k][p], akq = A[k][q];
                    A[k][p] = c * akp - s * akq;
                    A[k][q] = s * akp + c * akq;
                }
                for (int k = 0; k < 8; ++k) {
                    const double apk = A[p][k], aqk = A[q][k];
                    A[p][k] = c * apk - s * aqk;
                    A[q][k] = s * apk + c * aqk;
                }
                for (int k = 0; k < 8; ++k) {
                    const double vkp = V[k][p], vkq = V[k][q];
                    V[k][p] = c * vkp - s * vkq;
                    V[k][q] = s * vkp + c * vkq;
                }
            }
    }
    for (int i = 0; i < 8; ++i)
        for (int j = 0; j < 8; ++j) {
            double acc = 0.0;
            for (int k = 0; k < 8; ++k) acc += V[i][k] * V[j][k] / sqrt(A[k][k]);
            prm.W[i * 8 + j] = (float)acc;
        }

    for (int a = 0; a < 8; ++a)
        prm.invnorm[a] = (float)(1.0 / sqrt(pow(5.0, 2.0 * a + 7.0) / (2.0 * a + 7.0)));

    const double pi = 3.14159265358979323846;
    const double fp = 4.0 * pi;
    double yc[NM];
    yc[0]  = 0.5 * sqrt(1.0 / pi);
    yc[1]  = yc[2] = yc[3] = sqrt(3.0 / (4.0 * pi));
    yc[4]  = yc[5] = yc[7] = 0.5 * sqrt(15.0 / pi);
    yc[6]  = 0.25 * sqrt(5.0 / pi);
    yc[8]  = 0.25 * sqrt(15.0 / pi);
    yc[9]  = yc[15] = 0.25 * sqrt(35.0 / (2.0 * pi));
    yc[10] = 0.5 * sqrt(105.0 / pi);
    yc[11] = yc[13] = 0.25 * sqrt(21.0 / (2.0 * pi));
    yc[12] = 0.25 * sqrt(7.0 / pi);
    yc[14] = 0.25 * sqrt(105.0 / pi);
    yc[16] = 0.75 * sqrt(35.0 / pi);
    yc[17] = yc[23] = 0.75 * sqrt(35.0 / (2.0 * pi));
    yc[18] = 0.75 * sqrt(5.0 / pi);
    yc[19] = yc[21] = 0.75 * sqrt(5.0 / (2.0 * pi));
    yc[20] = 3.0 / 16.0 * sqrt(1.0 / pi);
    yc[22] = 3.0 / 8.0 * sqrt(5.0 / pi);
    yc[24] = 3.0 / 16.0 * sqrt(35.0 / pi);
    for (int m = 0; m < NM; ++m) prm.ycoef[m] = (float)(yc[m] * fp);

    for (int l = 0; l <= 4; ++l) prm.lscale[l] = (float)(pi * sqrt(8.0 / (2.0 * l + 1.0)));
    const float rt2 = 1.41421356237309515f;
    prm.pairf[0] = 1.f; prm.pairf[1] = rt2; prm.pairf[2] = rt2;
    prm.pairf[3] = 1.f; prm.pairf[4] = rt2; prm.pairf[5] = 1.f;

    soap_kernel<<<nsite, 256, 0, stream>>>(pos, Z, out, prm);
}